// Round 5
// baseline (257.395 us; speedup 1.0000x reference)
//
#include <hip/hip_runtime.h>
#include <hip/hip_bf16.h>

// TextEncoderBlock R4: attention back to KVBLK=32 (low VGPR) + K/V register
// prefetch + 8x finer kv-chunks (256 kv each) + bf16 partials.
// Swapped-QK^T lane-local softmax, SwiGLU fused FFN GEMM, RoPE fused QKV.
// B=1 L=2048 EMBD=960 FFN=2560 QH=15 KVH=5 HD=64

typedef __hip_bfloat16 bf16;
typedef __attribute__((ext_vector_type(8))) short bf16x8;
typedef __attribute__((ext_vector_type(4))) float f32x4;
typedef __attribute__((ext_vector_type(16))) float f32x16;

#define EPS 1.1920929e-07f

__device__ __forceinline__ void gload_lds16(const bf16* g, bf16* l) {
  __builtin_amdgcn_global_load_lds(
      (const __attribute__((address_space(1))) unsigned int*)g,
      (__attribute__((address_space(3))) unsigned int*)l, 16, 0, 0);
}

__device__ __forceinline__ unsigned short f2bfu(float f) {
  __hip_bfloat16 b = __float2bfloat16(f);
  return *reinterpret_cast<unsigned short*>(&b);
}
__device__ __forceinline__ float bfu2f(unsigned short u) {
  return __uint_as_float(((unsigned int)u) << 16);
}
__device__ __forceinline__ unsigned int cvtpk(float lo, float hi_) {
  unsigned int r;
  asm("v_cvt_pk_bf16_f32 %0, %1, %2" : "=v"(r) : "v"(lo), "v"(hi_));
  return r;
}

// ---------------- fused prep: 7 weight transposes + rope table --------------
__device__ void do_transpose(float (*tile)[65], const float* __restrict__ W,
                             bf16* __restrict__ WT, int K, int N, int bx, int by,
                             int map) {
  const int k0 = by * 64, n0 = bx * 64;
  const int tx = threadIdx.x & 63, ty = threadIdx.x >> 6;
#pragma unroll
  for (int i = 0; i < 16; ++i) {
    int r = ty + i * 4;
    tile[r][tx] = W[(size_t)(k0 + r) * N + n0 + tx];
  }
  __syncthreads();
#pragma unroll
  for (int i = 0; i < 16; ++i) {
    int r = ty + i * 4;
    int v = n0 + r;
    int row = (map == 0) ? v : ((v >> 4) << 5) + (v & 15) + (map == 2 ? 16 : 0);
    WT[(size_t)row * K + k0 + tx] = __float2bfloat16(tile[tx][r]);
  }
}

__launch_bounds__(256)
__global__ void prep_k(const float* __restrict__ wq, const float* __restrict__ wk,
                       const float* __restrict__ wv, const float* __restrict__ wo,
                       const float* __restrict__ wg, const float* __restrict__ wu,
                       const float* __restrict__ wd, bf16* __restrict__ wqkvT,
                       bf16* __restrict__ woT, bf16* __restrict__ wguT,
                       bf16* __restrict__ wdT, float2* __restrict__ cstab) {
  __shared__ float tile[64][65];
  int b = blockIdx.x;
  if (b < 225) {
    do_transpose(tile, wq, wqkvT, 960, 960, b % 15, b / 15, 0);
  } else if (b < 300) {
    b -= 225;
    do_transpose(tile, wk, wqkvT + 921600, 960, 320, b % 5, b / 5, 0);
  } else if (b < 375) {
    b -= 300;
    do_transpose(tile, wv, wqkvT + 1228800, 960, 320, b % 5, b / 5, 0);
  } else if (b < 600) {
    b -= 375;
    do_transpose(tile, wo, woT, 960, 960, b % 15, b / 15, 0);
  } else if (b < 1200) {
    b -= 600;
    do_transpose(tile, wg, wguT, 960, 2560, b % 40, b / 40, 1);
  } else if (b < 1800) {
    b -= 1200;
    do_transpose(tile, wu, wguT, 960, 2560, b % 40, b / 40, 2);
  } else if (b < 2400) {
    b -= 1800;
    do_transpose(tile, wd, wdT, 2560, 960, b % 15, b / 15, 0);
  } else {
    const int idx = (b - 2400) * 256 + threadIdx.x;
    const int pos = idx >> 5, d = idx & 31;
    float inv = powf(10000.f, -(float)d * (1.f / 32.f));
    float rad = (float)pos * inv;
    cstab[idx] = make_float2(cosf(rad), sinf(rad));
  }
}

// ---------------- rmsnorm ---------------------------------------------------
__launch_bounds__(256)
__global__ void rmsnorm_k(const float* __restrict__ x, const float* __restrict__ g,
                          bf16* __restrict__ out) {
  const int row = blockIdx.x;
  const float* xr = x + (size_t)row * 960;
  const int t = threadIdx.x;
  float4 v = {0.f, 0.f, 0.f, 0.f};
  float ss = 0.f;
  if (t < 240) {
    v = *reinterpret_cast<const float4*>(&xr[t * 4]);
    ss = v.x * v.x + v.y * v.y + v.z * v.z + v.w * v.w;
  }
#pragma unroll
  for (int off = 32; off; off >>= 1) ss += __shfl_down(ss, off);
  __shared__ float red[4];
  __shared__ float s_scale;
  if ((t & 63) == 0) red[t >> 6] = ss;
  __syncthreads();
  if (t == 0) {
    float tot = red[0] + red[1] + red[2] + red[3];
    s_scale = rsqrtf(tot * (1.f / 960.f) + EPS);
  }
  __syncthreads();
  if (t < 240) {
    const float sc = s_scale;
    const float4 gv = *reinterpret_cast<const float4*>(&g[t * 4]);
    ushort4 o;
    o.x = f2bfu(v.x * sc * gv.x);
    o.y = f2bfu(v.y * sc * gv.y);
    o.z = f2bfu(v.z * sc * gv.z);
    o.w = f2bfu(v.w * sc * gv.w);
    *reinterpret_cast<ushort4*>(&out[(size_t)row * 960 + t * 4]) = o;
  }
}

// ---------------- FFN GEMM 128x128, fused SwiGLU epilogue -------------------
__launch_bounds__(256)
__global__ void gemm_ffn(const bf16* __restrict__ A, const bf16* __restrict__ BT,
                         bf16* __restrict__ actb) {
  const int K = 960;
  __shared__ __align__(16) bf16 sA[2][128 * 32];
  __shared__ __align__(16) bf16 sB[2][128 * 32];
  const int t = threadIdx.x, w = t >> 6, lane = t & 63;
  const int lg = lane >> 4, lr = lane & 15;
  const int wm = w >> 1, wn = w & 1;
  const int m0 = blockIdx.y * 128, n0 = blockIdx.x * 128;
  f32x4 acc[4][4] = {};
  const int nsteps = K / 32;

  auto stage = [&](int buf, int ks) {
    const int k0 = ks * 32;
#pragma unroll
    for (int i = 0; i < 2; ++i) {
      int c = w * 128 + i * 64 + lane;
      int r = c >> 2, kc = (c & 3) * 8;
      gload_lds16(A + (size_t)(m0 + r) * K + k0 + kc, &sA[buf][c * 8]);
      gload_lds16(BT + (size_t)(n0 + r) * K + k0 + kc, &sB[buf][c * 8]);
    }
  };

  stage(0, 0);
  __syncthreads();
  int cur = 0;
  for (int ks = 0; ks < nsteps; ++ks) {
    if (ks + 1 < nsteps) stage(cur ^ 1, ks + 1);
    bf16x8 af[4], bfr[4];
#pragma unroll
    for (int mi = 0; mi < 4; ++mi)
      af[mi] = *reinterpret_cast<const bf16x8*>(&sA[cur][(wm * 64 + mi * 16 + lr) * 32 + lg * 8]);
#pragma unroll
    for (int ni = 0; ni < 4; ++ni)
      bfr[ni] = *reinterpret_cast<const bf16x8*>(&sB[cur][(wn * 64 + ni * 16 + lr) * 32 + lg * 8]);
#pragma unroll
    for (int mi = 0; mi < 4; ++mi)
#pragma unroll
      for (int ni = 0; ni < 4; ++ni)
        acc[mi][ni] = __builtin_amdgcn_mfma_f32_16x16x32_bf16(af[mi], bfr[ni], acc[mi][ni], 0, 0, 0);
    __syncthreads();
    cur ^= 1;
  }

  const int colbase = n0 + wn * 64;
#pragma unroll
  for (int mi = 0; mi < 4; ++mi) {
    const int row = m0 + wm * 64 + mi * 16 + lg * 4;
#pragma unroll
    for (int p = 0; p < 2; ++p) {
      const int oc = ((colbase >> 5) + p) * 16 + lr;
#pragma unroll
      for (int r = 0; r < 4; ++r) {
        float gf = acc[mi][2 * p][r], uf = acc[mi][2 * p + 1][r];
        float s = gf / (1.f + __expf(-gf));
        actb[(size_t)(row + r) * 2560 + oc] = __float2bfloat16(s * uf);
      }
    }
  }
}

// ---------------- GEMM 64x128 (small N): MODE 2 += Res, MODE 3 split kv -----
template <int MODE>
__launch_bounds__(256)
__global__ void gemm_bt64(const bf16* __restrict__ A, const bf16* __restrict__ BT,
                          const float* __restrict__ Res, float* __restrict__ Cf,
                          int N, int K) {
  __shared__ __align__(16) bf16 sA[2][64 * 32];
  __shared__ __align__(16) bf16 sB[2][128 * 32];
  const int t = threadIdx.x, w = t >> 6, lane = t & 63;
  const int lg = lane >> 4, lr = lane & 15;
  const int wm = w >> 1, wn = w & 1;
  const int m0 = blockIdx.y * 64, n0 = blockIdx.x * 128;
  f32x4 acc[2][4] = {};
  const int nsteps = K / 32;

  auto stage = [&](int buf, int ks) {
    const int k0 = ks * 32;
    {
      int c = t;
      int r = c >> 2, kc = (c & 3) * 8;
      gload_lds16(A + (size_t)(m0 + r) * K + k0 + kc, &sA[buf][c * 8]);
    }
#pragma unroll
    for (int i = 0; i < 2; ++i) {
      int c = i * 256 + t;
      int r = c >> 2, kc = (c & 3) * 8;
      int br = n0 + r;
      if (br >= N) br = N - 1;
      gload_lds16(BT + (size_t)br * K + k0 + kc, &sB[buf][c * 8]);
    }
  };

  stage(0, 0);
  __syncthreads();
  int cur = 0;
  for (int ks = 0; ks < nsteps; ++ks) {
    if (ks + 1 < nsteps) stage(cur ^ 1, ks + 1);
    bf16x8 af[2], bfr[4];
#pragma unroll
    for (int mi = 0; mi < 2; ++mi)
      af[mi] = *reinterpret_cast<const bf16x8*>(&sA[cur][(wm * 32 + mi * 16 + lr) * 32 + lg * 8]);
#pragma unroll
    for (int ni = 0; ni < 4; ++ni)
      bfr[ni] = *reinterpret_cast<const bf16x8*>(&sB[cur][(wn * 64 + ni * 16 + lr) * 32 + lg * 8]);
#pragma unroll
    for (int mi = 0; mi < 2; ++mi)
#pragma unroll
      for (int ni = 0; ni < 4; ++ni)
        acc[mi][ni] = __builtin_amdgcn_mfma_f32_16x16x32_bf16(af[mi], bfr[ni], acc[mi][ni], 0, 0, 0);
    __syncthreads();
    cur ^= 1;
  }

#pragma unroll
  for (int mi = 0; mi < 2; ++mi) {
    const int row = m0 + wm * 32 + mi * 16 + lg * 4;
#pragma unroll
    for (int ni = 0; ni < 4; ++ni) {
      const int col = n0 + wn * 64 + ni * 16 + lr;
      if (col < N) {
#pragma unroll
        for (int r = 0; r < 4; ++r) {
          float v = acc[mi][ni][r];
          size_t idx = (size_t)(row + r) * N + col;
          if (MODE == 2) {
            Cf[idx] = v + Res[idx];
          } else {
            int rr = row + r;
            if (col < 320)
              Cf[(size_t)rr * 320 + col] = v;
            else
              Cf[655360 + (size_t)rr * 320 + (col - 320)] = v;
          }
        }
      }
    }
  }
}

// ---------------- QKV GEMM 64x128 with fused RoPE + V-transpose epilogue ----
__launch_bounds__(256)
__global__ void gemm_qkv(const bf16* __restrict__ A, const bf16* __restrict__ BT,
                         const float2* __restrict__ cstab, bf16* __restrict__ qr,
                         bf16* __restrict__ kr, bf16* __restrict__ vT) {
  const int N = 1600, K = 960;
  __shared__ __align__(16) bf16 sA[2][64 * 32];
  __shared__ __align__(16) bf16 sB[2][128 * 32];
  const int t = threadIdx.x, w = t >> 6, lane = t & 63;
  const int lg = lane >> 4, lr = lane & 15;
  const int wm = w >> 1, wn = w & 1;
  const int m0 = blockIdx.y * 64, n0 = blockIdx.x * 128;
  f32x4 acc[2][4] = {};
  const int nsteps = K / 32;

  auto stage = [&](int buf, int ks) {
    const int k0 = ks * 32;
    {
      int c = t;
      int r = c >> 2, kc = (c & 3) * 8;
      gload_lds16(A + (size_t)(m0 + r) * K + k0 + kc, &sA[buf][c * 8]);
    }
#pragma unroll
    for (int i = 0; i < 2; ++i) {
      int c = i * 256 + t;
      int r = c >> 2, kc = (c & 3) * 8;
      int br = n0 + r;
      if (br >= N) br = N - 1;
      gload_lds16(BT + (size_t)br * K + k0 + kc, &sB[buf][c * 8]);
    }
  };

  stage(0, 0);
  __syncthreads();
  int cur = 0;
  for (int ks = 0; ks < nsteps; ++ks) {
    if (ks + 1 < nsteps) stage(cur ^ 1, ks + 1);
    bf16x8 af[2], bfr[4];
#pragma unroll
    for (int mi = 0; mi < 2; ++mi)
      af[mi] = *reinterpret_cast<const bf16x8*>(&sA[cur][(wm * 32 + mi * 16 + lr) * 32 + lg * 8]);
#pragma unroll
    for (int ni = 0; ni < 4; ++ni)
      bfr[ni] = *reinterpret_cast<const bf16x8*>(&sB[cur][(wn * 64 + ni * 16 + lr) * 32 + lg * 8]);
#pragma unroll
    for (int mi = 0; mi < 2; ++mi)
#pragma unroll
      for (int ni = 0; ni < 4; ++ni)
        acc[mi][ni] = __builtin_amdgcn_mfma_f32_16x16x32_bf16(af[mi], bfr[ni], acc[mi][ni], 0, 0, 0);
    __syncthreads();
    cur ^= 1;
  }

  const int colbase = n0 + wn * 64;
  if (colbase >= 1600) return;
  if (colbase < 1280) {
    const bool isq = colbase < 960;
    bf16* dst = isq ? qr : kr;
    const int ncols = isq ? 960 : 320;
    const int cb = isq ? colbase : colbase - 960;
#pragma unroll
    for (int mi = 0; mi < 2; ++mi) {
      const int row = m0 + wm * 32 + mi * 16 + lg * 4;
#pragma unroll
      for (int ni = 0; ni < 2; ++ni) {
        const int d = ni * 16 + lr;
#pragma unroll
        for (int r = 0; r < 4; ++r) {
          const int pos = row + r;
          float2 cs = cstab[pos * 32 + d];
          float x1 = acc[mi][ni][r], x2 = acc[mi][ni + 2][r];
          dst[(size_t)pos * ncols + cb + d] = __float2bfloat16(x1 * cs.x - x2 * cs.y);
          dst[(size_t)pos * ncols + cb + d + 32] = __float2bfloat16(x2 * cs.x + x1 * cs.y);
        }
      }
    }
  } else {
#pragma unroll
    for (int mi = 0; mi < 2; ++mi) {
      const int row = m0 + wm * 32 + mi * 16 + lg * 4;
#pragma unroll
      for (int ni = 0; ni < 4; ++ni) {
        const int vc = colbase - 1280 + ni * 16 + lr;
        ushort4 pk;
        pk.x = f2bfu(acc[mi][ni][0]);
        pk.y = f2bfu(acc[mi][ni][1]);
        pk.z = f2bfu(acc[mi][ni][2]);
        pk.w = f2bfu(acc[mi][ni][3]);
        *reinterpret_cast<ushort4*>(&vT[(size_t)vc * 2048 + row]) = pk;
      }
    }
  }
}

// ---------------- swapped-QK^T flash attention, KVBLK=32 + prefetch ---------
// grid (64 qt, 15 head, 8 chunk of 256 kv), block 64 (1 wave).
// Lane owns q = q0+(lane&31). K/V for tile kb+1 issued before computing kb.
__launch_bounds__(64)
__global__ void attn_part4(const bf16* __restrict__ q, const bf16* __restrict__ k,
                           const bf16* __restrict__ vT, bf16* __restrict__ pacc,
                           float* __restrict__ pml) {
  const int qt = blockIdx.x, head = blockIdx.y, c = blockIdx.z;
  const int t0 = c * 8;
  if (t0 > qt) return;                 // ntiles = qt+1 (32-kv tiles)
  const int t1 = min(t0 + 8, qt + 1);
  const int lane = threadIdx.x & 63;
  const int ql = lane & 31;
  const int hi = lane >> 5;
  const int q0 = qt * 32;
  const int kvh = head / 3;
  const int qrow = q0 + ql;
  const int kvoff = 4 * hi;

  bf16x8 qf[4];
#pragma unroll
  for (int i = 0; i < 4; ++i)
    qf[i] = *reinterpret_cast<const bf16x8*>(
        &q[(size_t)(q0 + ql) * 960 + head * 64 + i * 16 + hi * 8]);

  f32x16 acc0 = {}, acc1 = {};
  float mrun = -1e30f, lrun = 0.f;
  const size_t krow = (size_t)ql * 320 + kvh * 64 + hi * 8;
  const size_t vrow0 = (size_t)(kvh * 64 + ql) * 2048 + hi * 8;
  const size_t vrow1 = vrow0 + 32 * 2048;

  // preload tile t0
  bf16x8 kc0, kc1, kc2, kc3, vc0, vc1, vc2, vc3;
  {
    const size_t kb0 = krow + (size_t)t0 * 32 * 320;
    kc0 = *reinterpret_cast<const bf16x8*>(&k[kb0]);
    kc1 = *reinterpret_cast<const bf16x8*>(&k[kb0 + 16]);
    kc2 = *reinterpret_cast<const bf16x8*>(&k[kb0 + 32]);
    kc3 = *reinterpret_cast<const bf16x8*>(&k[kb0 + 48]);
    vc0 = *reinterpret_cast<const bf16x8*>(&vT[vrow0 + t0 * 32]);
    vc1 = *reinterpret_cast<const bf16x8*>(&vT[vrow0 + t0 * 32 + 16]);
    vc2 = *reinterpret_cast<const bf16x8*>(&vT[vrow1 + t0 * 32]);
    vc3 = *reinterpret_cast<const bf16x8*>(&vT[vrow1 + t0 * 32 + 16]);
  }

  for (int kb = t0; kb < t1; ++kb) {
    // ---- issue next tile's K/V loads (prefetch; redundant re-load on last) --
    const int nb = (kb + 1 < t1) ? kb + 1 : kb;
    const size_t kbn = krow + (size_t)nb * 32 * 320;
    bf16x8 kn0 = *reinterpret_cast<const bf16x8*>(&k[kbn]);
    bf16x8 kn1 = *reinterpret_cast<const bf16x8*>(&k[kbn + 16]);
    bf16x8 kn2 = *reinterpret_cast<const bf16x8*>(&k[kbn + 32]);
    bf16x8 kn3 = *reinterpret_cast<const bf16x8*>(&k[kbn + 48]);
    bf16x8 vn0 = *reinterpret_cast<const bf16x8*>(&vT[vrow0 + nb * 32]);
    bf16x8 vn1 = *reinterpret_cast<const bf16x8*>(&vT[vrow0 + nb * 32 + 16]);
    bf16x8 vn2 = *reinterpret_cast<const bf16x8*>(&vT[vrow1 + nb * 32]);
    bf16x8 vn3 = *reinterpret_cast<const bf16x8*>(&vT[vrow1 + nb * 32 + 16]);

    // ---- S^T = K · Q^T ----
    f32x16 s = {};
    s = __builtin_amdgcn_mfma_f32_32x32x16_bf16(kc0, qf[0], s, 0, 0, 0);
    s = __builtin_amdgcn_mfma_f32_32x32x16_bf16(kc1, qf[1], s, 0, 0, 0);
    s = __builtin_amdgcn_mfma_f32_32x32x16_bf16(kc2, qf[2], s, 0, 0, 0);
    s = __builtin_amdgcn_mfma_f32_32x32x16_bf16(kc3, qf[3], s, 0, 0, 0);

    const int kvb = kb * 32;
    if (kvb + 31 > qrow) {
#pragma unroll
      for (int r = 0; r < 16; ++r) {
        const int kv = kvb + kvoff + (r & 3) + 8 * (r >> 2);
        float sv = s[r] * 0.125f;
        s[r] = (kv > qrow) ? -1e30f : sv;
      }
    } else {
#pragma unroll
      for (int r = 0; r < 16; ++r) s[r] *= 0.125f;
    }

    // ---- lane-local softmax (one cross-lane hop) ----
    float tm = s[0];
#pragma unroll
    for (int r = 1; r < 16; ++r) tm = fmaxf(tm, s[r]);
    tm = fmaxf(tm, __shfl_xor(tm, 32));
    const float mn = fmaxf(mrun, tm);
    const float ef = __expf(mrun - mn);
    mrun = mn;
    float ts = 0.f;
#pragma unroll
    for (int r = 0; r < 16; ++r) {
      float p = __expf(s[r] - mn);
      s[r] = p;
      ts += p;
    }
    ts += __shfl_xor(ts, 32);
    lrun = lrun * ef + ts;
#pragma unroll
    for (int r = 0; r < 16; ++r) { acc0[r] *= ef; acc1[r] *= ef; }

    // ---- P^T -> bf16 B-fragments (cvt_pk + xor32 exchange) ----
    unsigned int a0 = cvtpk(s[0], s[1]), a1 = cvtpk(s[2], s[3]);
    unsigned int a2 = cvtpk(s[4], s[5]), a3 = cvtpk(s[6], s[7]);
    unsigned int b0 = cvtpk(s[8], s[9]), b1 = cvtpk(s[10], s[11]);
    unsigned int b2 = cvtpk(s[12], s[13]), b3 = cvtpk(s[14], s[15]);
    unsigned int x0 = __shfl_xor(a0, 32), x1 = __shfl_xor(a1, 32);
    unsigned int x2 = __shfl_xor(a2, 32), x3 = __shfl_xor(a3, 32);
    unsigned int y0 = __shfl_xor(b0, 32), y1 = __shfl_xor(b1, 32);
    unsigned int y2 = __shfl_xor(b2, 32), y3 = __shfl_xor(b3, 32);
    union { unsigned int u[4]; bf16x8 v; } f0, f1;
    f0.u[0] = hi ? x2 : a0; f0.u[1] = hi ? x3 : a1;
    f0.u[2] = hi ? a2 : x0; f0.u[3] = hi ? a3 : x1;
    f1.u[0] = hi ? y2 : b0; f1.u[1] = hi ? y3 : b1;
    f1.u[2] = hi ? b2 : y0; f1.u[3] = hi ? b3 : y1;

    // ---- O^T += V^T · P^T ----
    acc0 = __builtin_amdgcn_mfma_f32_32x32x16_bf16(vc0, f0.v, acc0, 0, 0, 0);
    acc1 = __builtin_amdgcn_mfma_f32_32x32x16_bf16(vc2, f0.v, acc1, 0, 0, 0);
    acc0 = __builtin_amdgcn_mfma_f32_32x32x16_bf16(vc1, f1.v, acc0, 0, 0, 0);
    acc1 = __builtin_amdgcn_mfma_f32_32x32x16_bf16(vc3, f1.v, acc1, 0, 0, 0);

    // ---- rotate prefetched regs into current ----
    kc0 = kn0; kc1 = kn1; kc2 = kn2; kc3 = kn3;
    vc0 = vn0; vc1 = vn1; vc2 = vn2; vc3 = vn3;
  }

  // ---- write partials (bf16): pacc[job][d=64][q=32] ----
  const size_t base = (((size_t)head * 64 + qt) * 8 + c) * 2048;
#pragma unroll
  for (int r = 0; r < 16; ++r) {
    const int row = (r & 3) + 8 * (r >> 2) + kvoff;
    pacc[base + (size_t)row * 32 + ql] = __float2bfloat16(acc0[r]);
    pacc[base + (size_t)(row + 32) * 32 + ql] = __float2bfloat16(acc1[r]);
  }
  const size_t mb = (((size_t)head * 64 + qt) * 8 + c) * 64;
  if (!hi) {
    pml[mb + ql * 2] = mrun;
    pml[mb + ql * 2 + 1] = lrun;
  }
}

// ---------------- attention merge: combine <=8 chunks -----------------------
__launch_bounds__(256)
__global__ void attn_merge3(const bf16* __restrict__ pacc, const float* __restrict__ pml,
                            bf16* __restrict__ ctx) {
  const int qt = blockIdx.x, head = blockIdx.y;
  const int nch = qt / 8 + 1;
  const size_t base = (((size_t)head * 64 + qt) * 8) * 2048;
  const size_t mb = (((size_t)head * 64 + qt) * 8) * 64;
  for (int i = threadIdx.x; i < 2048; i += 256) {
    const int qi = i >> 6, d = i & 63;
    float m = -1e30f;
    for (int c = 0; c < nch; ++c) m = fmaxf(m, pml[mb + c * 64 + qi * 2]);
    float lsum = 0.f, o = 0.f;
    for (int c = 0; c < nch; ++c) {
      float e = __expf(pml[mb + c * 64 + qi * 2] - m);
      lsum += pml[mb + c * 64 + qi * 2 + 1] * e;
      o += __bfloat162float(pacc[base + c * 2048 + d * 32 + qi]) * e;
    }
    ctx[(size_t)(qt * 32 + qi) * 960 + head * 64 + d] = __float2bfloat16(o / lsum);
  }
}

// ---------------- launch ----------------------------------------------------
extern "C" void kernel_launch(void* const* d_in, const int* in_sizes, int n_in,
                              void* d_out, int out_size, void* d_ws, size_t ws_size,
                              hipStream_t stream) {
  const float* x  = (const float*)d_in[0];
  const float* wq = (const float*)d_in[1];
  const float* wk = (const float*)d_in[2];
  const float* wv = (const float*)d_in[3];
  const float* wo = (const float*)d_in[4];
  const float* wg = (const float*)d_in[5];
  const float* wu = (const float*)d_in[6];
  const float* wd = (const float*)d_in[7];
  const float* g1 = (const float*)d_in[8];
  const float* g2 = (const float*)d_in[9];
  float* out = (float*)d_out;

  char* ws = (char*)d_ws;
  bf16*   wT   = (bf16*)ws;                        // 19,660,800 B
  bf16*   pacc = (bf16*)(ws + 19660800);           // 31,457,280 B (bf16 partials)
  float*  pml  = (float*)(ws + 51118080);          // 1,966,080 B
  bf16*   hbuf = (bf16*)(ws + 53084160);           // 3,932,160
  bf16*   qr   = (bf16*)(ws + 57016320);           // 3,932,160
  bf16*   kr   = (bf16*)(ws + 60948480);           // 1,310,720
  bf16*   vT   = (bf16*)(ws + 62259200);           // 1,310,720
  bf16*   ctx  = (bf16*)(ws + 63569920);           // 3,932,160
  float*  x2   = (float*)(ws + 67502080);          // 7,864,320 (ends 75,366,400)
  float2* cst  = (float2*)(ws + 74842112);         // 524,288, overlaps x2 tail:
                                                   // cst dead before x2 written
  bf16*   actb = (bf16*)(ws + 19660800);           // reuse pacc region after merge

  bf16* wqkvT = wT;           // 1600 rows x K=960: wq | wk | wv
  bf16* wkT  = wT + 921600;
  bf16* woT  = wT + 1536000;  // 960x960
  bf16* wguT = wT + 2457600;  // 5120x960 interleaved [gate16|up16]
  bf16* wdT  = wT + 7372800;  // 960x2560

  dim3 blk(256);
  prep_k<<<2656, blk, 0, stream>>>(wq, wk, wv, wo, wg, wu, wd,
                                   wqkvT, woT, wguT, wdT, cst);

  rmsnorm_k<<<2048, blk, 0, stream>>>(x, g1, hbuf);
  gemm_qkv<<<dim3(13, 32), blk, 0, stream>>>(hbuf, wqkvT, cst, qr, kr, vT);
  attn_part4<<<dim3(64, 15, 8), dim3(64), 0, stream>>>(qr, kr, vT, pacc, pml);
  attn_merge3<<<dim3(64, 15), blk, 0, stream>>>(pacc, pml, ctx);
  gemm_bt64<2><<<dim3(8, 32), blk, 0, stream>>>(ctx, woT, x, x2, 960, 960);
  rmsnorm_k<<<2048, blk, 0, stream>>>(x2, g2, hbuf);
  gemm_ffn<<<dim3(40, 16), blk, 0, stream>>>(hbuf, wguT, actb);
  gemm_bt64<2><<<dim3(8, 32), blk, 0, stream>>>(actb, wdT, x2, out, 960, 2560);
  rmsnorm_k<<<2048, blk, 0, stream>>>(x2, g1, hbuf);
  gemm_bt64<3><<<dim3(5, 32), blk, 0, stream>>>(hbuf, wkT, nullptr, out + 1966080, 640, 960);
}

// Round 6
// 234.526 us; speedup vs baseline: 1.0975x; 1.0975x over previous
//
#include <hip/hip_runtime.h>
#include <hip/hip_bf16.h>

// TextEncoderBlock R5: V stored kv-block-tiled (vTb[posblk][320][32]) to kill
// the 4KB-stride channel aliasing in attention PV loads; QK 2-chain split;
// setprio around MFMA; 8-wave gemm_bt64. Swapped-QK^T lane-local softmax.
// B=1 L=2048 EMBD=960 FFN=2560 QH=15 KVH=5 HD=64

typedef __hip_bfloat16 bf16;
typedef __attribute__((ext_vector_type(8))) short bf16x8;
typedef __attribute__((ext_vector_type(4))) float f32x4;
typedef __attribute__((ext_vector_type(16))) float f32x16;

#define EPS 1.1920929e-07f

__device__ __forceinline__ void gload_lds16(const bf16* g, bf16* l) {
  __builtin_amdgcn_global_load_lds(
      (const __attribute__((address_space(1))) unsigned int*)g,
      (__attribute__((address_space(3))) unsigned int*)l, 16, 0, 0);
}

__device__ __forceinline__ unsigned short f2bfu(float f) {
  __hip_bfloat16 b = __float2bfloat16(f);
  return *reinterpret_cast<unsigned short*>(&b);
}
__device__ __forceinline__ float bfu2f(unsigned short u) {
  return __uint_as_float(((unsigned int)u) << 16);
}
__device__ __forceinline__ unsigned int cvtpk(float lo, float hi_) {
  unsigned int r;
  asm("v_cvt_pk_bf16_f32 %0, %1, %2" : "=v"(r) : "v"(lo), "v"(hi_));
  return r;
}

// ---------------- fused prep: 7 weight transposes + rope table --------------
__device__ void do_transpose(float (*tile)[65], const float* __restrict__ W,
                             bf16* __restrict__ WT, int K, int N, int bx, int by,
                             int map) {
  const int k0 = by * 64, n0 = bx * 64;
  const int tx = threadIdx.x & 63, ty = threadIdx.x >> 6;
#pragma unroll
  for (int i = 0; i < 16; ++i) {
    int r = ty + i * 4;
    tile[r][tx] = W[(size_t)(k0 + r) * N + n0 + tx];
  }
  __syncthreads();
#pragma unroll
  for (int i = 0; i < 16; ++i) {
    int r = ty + i * 4;
    int v = n0 + r;
    int row = (map == 0) ? v : ((v >> 4) << 5) + (v & 15) + (map == 2 ? 16 : 0);
    WT[(size_t)row * K + k0 + tx] = __float2bfloat16(tile[tx][r]);
  }
}

__launch_bounds__(256)
__global__ void prep_k(const float* __restrict__ wq, const float* __restrict__ wk,
                       const float* __restrict__ wv, const float* __restrict__ wo,
                       const float* __restrict__ wg, const float* __restrict__ wu,
                       const float* __restrict__ wd, bf16* __restrict__ wqkvT,
                       bf16* __restrict__ woT, bf16* __restrict__ wguT,
                       bf16* __restrict__ wdT, float2* __restrict__ cstab) {
  __shared__ float tile[64][65];
  int b = blockIdx.x;
  if (b < 225) {
    do_transpose(tile, wq, wqkvT, 960, 960, b % 15, b / 15, 0);
  } else if (b < 300) {
    b -= 225;
    do_transpose(tile, wk, wqkvT + 921600, 960, 320, b % 5, b / 5, 0);
  } else if (b < 375) {
    b -= 300;
    do_transpose(tile, wv, wqkvT + 1228800, 960, 320, b % 5, b / 5, 0);
  } else if (b < 600) {
    b -= 375;
    do_transpose(tile, wo, woT, 960, 960, b % 15, b / 15, 0);
  } else if (b < 1200) {
    b -= 600;
    do_transpose(tile, wg, wguT, 960, 2560, b % 40, b / 40, 1);
  } else if (b < 1800) {
    b -= 1200;
    do_transpose(tile, wu, wguT, 960, 2560, b % 40, b / 40, 2);
  } else if (b < 2400) {
    b -= 1800;
    do_transpose(tile, wd, wdT, 2560, 960, b % 15, b / 15, 0);
  } else {
    const int idx = (b - 2400) * 256 + threadIdx.x;
    const int pos = idx >> 5, d = idx & 31;
    float inv = powf(10000.f, -(float)d * (1.f / 32.f));
    float rad = (float)pos * inv;
    cstab[idx] = make_float2(cosf(rad), sinf(rad));
  }
}

// ---------------- rmsnorm ---------------------------------------------------
__launch_bounds__(256)
__global__ void rmsnorm_k(const float* __restrict__ x, const float* __restrict__ g,
                          bf16* __restrict__ out) {
  const int row = blockIdx.x;
  const float* xr = x + (size_t)row * 960;
  const int t = threadIdx.x;
  float4 v = {0.f, 0.f, 0.f, 0.f};
  float ss = 0.f;
  if (t < 240) {
    v = *reinterpret_cast<const float4*>(&xr[t * 4]);
    ss = v.x * v.x + v.y * v.y + v.z * v.z + v.w * v.w;
  }
#pragma unroll
  for (int off = 32; off; off >>= 1) ss += __shfl_down(ss, off);
  __shared__ float red[4];
  __shared__ float s_scale;
  if ((t & 63) == 0) red[t >> 6] = ss;
  __syncthreads();
  if (t == 0) {
    float tot = red[0] + red[1] + red[2] + red[3];
    s_scale = rsqrtf(tot * (1.f / 960.f) + EPS);
  }
  __syncthreads();
  if (t < 240) {
    const float sc = s_scale;
    const float4 gv = *reinterpret_cast<const float4*>(&g[t * 4]);
    ushort4 o;
    o.x = f2bfu(v.x * sc * gv.x);
    o.y = f2bfu(v.y * sc * gv.y);
    o.z = f2bfu(v.z * sc * gv.z);
    o.w = f2bfu(v.w * sc * gv.w);
    *reinterpret_cast<ushort4*>(&out[(size_t)row * 960 + t * 4]) = o;
  }
}

// ---------------- FFN GEMM 128x128, fused SwiGLU epilogue -------------------
__launch_bounds__(256)
__global__ void gemm_ffn(const bf16* __restrict__ A, const bf16* __restrict__ BT,
                         bf16* __restrict__ actb) {
  const int K = 960;
  __shared__ __align__(16) bf16 sA[2][128 * 32];
  __shared__ __align__(16) bf16 sB[2][128 * 32];
  const int t = threadIdx.x, w = t >> 6, lane = t & 63;
  const int lg = lane >> 4, lr = lane & 15;
  const int wm = w >> 1, wn = w & 1;
  const int m0 = blockIdx.y * 128, n0 = blockIdx.x * 128;
  f32x4 acc[4][4] = {};
  const int nsteps = K / 32;

  auto stage = [&](int buf, int ks) {
    const int k0 = ks * 32;
#pragma unroll
    for (int i = 0; i < 2; ++i) {
      int c = w * 128 + i * 64 + lane;
      int r = c >> 2, kc = (c & 3) * 8;
      gload_lds16(A + (size_t)(m0 + r) * K + k0 + kc, &sA[buf][c * 8]);
      gload_lds16(BT + (size_t)(n0 + r) * K + k0 + kc, &sB[buf][c * 8]);
    }
  };

  stage(0, 0);
  __syncthreads();
  int cur = 0;
  for (int ks = 0; ks < nsteps; ++ks) {
    if (ks + 1 < nsteps) stage(cur ^ 1, ks + 1);
    bf16x8 af[4], bfr[4];
#pragma unroll
    for (int mi = 0; mi < 4; ++mi)
      af[mi] = *reinterpret_cast<const bf16x8*>(&sA[cur][(wm * 64 + mi * 16 + lr) * 32 + lg * 8]);
#pragma unroll
    for (int ni = 0; ni < 4; ++ni)
      bfr[ni] = *reinterpret_cast<const bf16x8*>(&sB[cur][(wn * 64 + ni * 16 + lr) * 32 + lg * 8]);
#pragma unroll
    for (int mi = 0; mi < 4; ++mi)
#pragma unroll
      for (int ni = 0; ni < 4; ++ni)
        acc[mi][ni] = __builtin_amdgcn_mfma_f32_16x16x32_bf16(af[mi], bfr[ni], acc[mi][ni], 0, 0, 0);
    __syncthreads();
    cur ^= 1;
  }

  const int colbase = n0 + wn * 64;
#pragma unroll
  for (int mi = 0; mi < 4; ++mi) {
    const int row = m0 + wm * 64 + mi * 16 + lg * 4;
#pragma unroll
    for (int p = 0; p < 2; ++p) {
      const int oc = ((colbase >> 5) + p) * 16 + lr;
#pragma unroll
      for (int r = 0; r < 4; ++r) {
        float gf = acc[mi][2 * p][r], uf = acc[mi][2 * p + 1][r];
        float s = gf / (1.f + __expf(-gf));
        actb[(size_t)(row + r) * 2560 + oc] = __float2bfloat16(s * uf);
      }
    }
  }
}

// ---------------- GEMM 64x128, 8 waves (512 thr): MODE 2 +=Res, MODE 3 kv ---
template <int MODE>
__launch_bounds__(512)
__global__ void gemm_bt64(const bf16* __restrict__ A, const bf16* __restrict__ BT,
                          const float* __restrict__ Res, float* __restrict__ Cf,
                          int N, int K) {
  __shared__ __align__(16) bf16 sA[2][64 * 32];
  __shared__ __align__(16) bf16 sB[2][128 * 32];
  const int t = threadIdx.x, w = t >> 6, lane = t & 63;
  const int lg = lane >> 4, lr = lane & 15;
  const int wm = w >> 2, wn = w & 3;  // 2 x 4 waves, each 32x32
  const int m0 = blockIdx.y * 64, n0 = blockIdx.x * 128;
  f32x4 acc[2][2] = {};
  const int nsteps = K / 32;

  auto stage = [&](int buf, int ks) {
    const int k0 = ks * 32;
    if (t < 256) {
      int c = t;
      int r = c >> 2, kc = (c & 3) * 8;
      gload_lds16(A + (size_t)(m0 + r) * K + k0 + kc, &sA[buf][c * 8]);
    }
    {
      int c = t;
      int r = c >> 2, kc = (c & 3) * 8;
      int br = n0 + r;
      if (br >= N) br = N - 1;
      gload_lds16(BT + (size_t)br * K + k0 + kc, &sB[buf][c * 8]);
    }
  };

  stage(0, 0);
  __syncthreads();
  int cur = 0;
  for (int ks = 0; ks < nsteps; ++ks) {
    if (ks + 1 < nsteps) stage(cur ^ 1, ks + 1);
    bf16x8 af[2], bfr[2];
#pragma unroll
    for (int mi = 0; mi < 2; ++mi)
      af[mi] = *reinterpret_cast<const bf16x8*>(&sA[cur][(wm * 32 + mi * 16 + lr) * 32 + lg * 8]);
#pragma unroll
    for (int ni = 0; ni < 2; ++ni)
      bfr[ni] = *reinterpret_cast<const bf16x8*>(&sB[cur][(wn * 32 + ni * 16 + lr) * 32 + lg * 8]);
#pragma unroll
    for (int mi = 0; mi < 2; ++mi)
#pragma unroll
      for (int ni = 0; ni < 2; ++ni)
        acc[mi][ni] = __builtin_amdgcn_mfma_f32_16x16x32_bf16(af[mi], bfr[ni], acc[mi][ni], 0, 0, 0);
    __syncthreads();
    cur ^= 1;
  }

#pragma unroll
  for (int mi = 0; mi < 2; ++mi) {
    const int row = m0 + wm * 32 + mi * 16 + lg * 4;
#pragma unroll
    for (int ni = 0; ni < 2; ++ni) {
      const int col = n0 + wn * 32 + ni * 16 + lr;
      if (col < N) {
#pragma unroll
        for (int r = 0; r < 4; ++r) {
          float v = acc[mi][ni][r];
          size_t idx = (size_t)(row + r) * N + col;
          if (MODE == 2) {
            Cf[idx] = v + Res[idx];
          } else {
            int rr = row + r;
            if (col < 320)
              Cf[(size_t)rr * 320 + col] = v;
            else
              Cf[655360 + (size_t)rr * 320 + (col - 320)] = v;
          }
        }
      }
    }
  }
}

// ---------------- QKV GEMM 64x128 with fused RoPE + V-tiled epilogue --------
// vTb layout: [posblk 0..63][d 0..319][pos_in_blk 0..31]
__launch_bounds__(256)
__global__ void gemm_qkv(const bf16* __restrict__ A, const bf16* __restrict__ BT,
                         const float2* __restrict__ cstab, bf16* __restrict__ qr,
                         bf16* __restrict__ kr, bf16* __restrict__ vTb) {
  const int N = 1600, K = 960;
  __shared__ __align__(16) bf16 sA[2][64 * 32];
  __shared__ __align__(16) bf16 sB[2][128 * 32];
  const int t = threadIdx.x, w = t >> 6, lane = t & 63;
  const int lg = lane >> 4, lr = lane & 15;
  const int wm = w >> 1, wn = w & 1;
  const int m0 = blockIdx.y * 64, n0 = blockIdx.x * 128;
  f32x4 acc[2][4] = {};
  const int nsteps = K / 32;

  auto stage = [&](int buf, int ks) {
    const int k0 = ks * 32;
    {
      int c = t;
      int r = c >> 2, kc = (c & 3) * 8;
      gload_lds16(A + (size_t)(m0 + r) * K + k0 + kc, &sA[buf][c * 8]);
    }
#pragma unroll
    for (int i = 0; i < 2; ++i) {
      int c = i * 256 + t;
      int r = c >> 2, kc = (c & 3) * 8;
      int br = n0 + r;
      if (br >= N) br = N - 1;
      gload_lds16(BT + (size_t)br * K + k0 + kc, &sB[buf][c * 8]);
    }
  };

  stage(0, 0);
  __syncthreads();
  int cur = 0;
  for (int ks = 0; ks < nsteps; ++ks) {
    if (ks + 1 < nsteps) stage(cur ^ 1, ks + 1);
    bf16x8 af[2], bfr[4];
#pragma unroll
    for (int mi = 0; mi < 2; ++mi)
      af[mi] = *reinterpret_cast<const bf16x8*>(&sA[cur][(wm * 32 + mi * 16 + lr) * 32 + lg * 8]);
#pragma unroll
    for (int ni = 0; ni < 4; ++ni)
      bfr[ni] = *reinterpret_cast<const bf16x8*>(&sB[cur][(wn * 64 + ni * 16 + lr) * 32 + lg * 8]);
#pragma unroll
    for (int mi = 0; mi < 2; ++mi)
#pragma unroll
      for (int ni = 0; ni < 4; ++ni)
        acc[mi][ni] = __builtin_amdgcn_mfma_f32_16x16x32_bf16(af[mi], bfr[ni], acc[mi][ni], 0, 0, 0);
    __syncthreads();
    cur ^= 1;
  }

  const int colbase = n0 + wn * 64;
  if (colbase >= 1600) return;
  if (colbase < 1280) {
    const bool isq = colbase < 960;
    bf16* dst = isq ? qr : kr;
    const int ncols = isq ? 960 : 320;
    const int cb = isq ? colbase : colbase - 960;
#pragma unroll
    for (int mi = 0; mi < 2; ++mi) {
      const int row = m0 + wm * 32 + mi * 16 + lg * 4;
#pragma unroll
      for (int ni = 0; ni < 2; ++ni) {
        const int d = ni * 16 + lr;
#pragma unroll
        for (int r = 0; r < 4; ++r) {
          const int pos = row + r;
          float2 cs = cstab[pos * 32 + d];
          float x1 = acc[mi][ni][r], x2 = acc[mi][ni + 2][r];
          dst[(size_t)pos * ncols + cb + d] = __float2bfloat16(x1 * cs.x - x2 * cs.y);
          dst[(size_t)pos * ncols + cb + d + 32] = __float2bfloat16(x2 * cs.x + x1 * cs.y);
        }
      }
    }
  } else {
#pragma unroll
    for (int mi = 0; mi < 2; ++mi) {
      const int row = m0 + wm * 32 + mi * 16 + lg * 4;  // pos base (mult of 4)
#pragma unroll
      for (int ni = 0; ni < 4; ++ni) {
        const int vc = colbase - 1280 + ni * 16 + lr;
        ushort4 pk;
        pk.x = f2bfu(acc[mi][ni][0]);
        pk.y = f2bfu(acc[mi][ni][1]);
        pk.z = f2bfu(acc[mi][ni][2]);
        pk.w = f2bfu(acc[mi][ni][3]);
        // vTb[(row>>5)][vc][row&31]
        *reinterpret_cast<ushort4*>(
            &vTb[((size_t)(row >> 5) * 320 + vc) * 32 + (row & 31)]) = pk;
      }
    }
  }
}

// ---------------- swapped-QK^T flash attention, KVBLK=32, tiled V -----------
// grid (64 qt, 15 head, 8 chunk of 256 kv), block 64 (1 wave).
__launch_bounds__(64)
__global__ void attn_part5(const bf16* __restrict__ q, const bf16* __restrict__ k,
                           const bf16* __restrict__ vTb, bf16* __restrict__ pacc,
                           float* __restrict__ pml) {
  const int qt = blockIdx.x, head = blockIdx.y, c = blockIdx.z;
  const int t0 = c * 8;
  if (t0 > qt) return;
  const int t1 = min(t0 + 8, qt + 1);
  const int lane = threadIdx.x & 63;
  const int ql = lane & 31;
  const int hi = lane >> 5;
  const int q0 = qt * 32;
  const int kvh = head / 3;
  const int qrow = q0 + ql;
  const int kvoff = 4 * hi;

  bf16x8 qf[4];
#pragma unroll
  for (int i = 0; i < 4; ++i)
    qf[i] = *reinterpret_cast<const bf16x8*>(
        &q[(size_t)(q0 + ql) * 960 + head * 64 + i * 16 + hi * 8]);

  f32x16 acc0 = {}, acc1 = {};
  float mrun = -1e30f, lrun = 0.f;
  const size_t krow = (size_t)ql * 320 + kvh * 64 + hi * 8;

  for (int kb = t0; kb < t1; ++kb) {
    const int kvb = kb * 32;
    // ---- K loads (row-strided 640B, no aliasing) ----
    const size_t kb0 = krow + (size_t)kvb * 320;
    bf16x8 kc0 = *reinterpret_cast<const bf16x8*>(&k[kb0]);
    bf16x8 kc1 = *reinterpret_cast<const bf16x8*>(&k[kb0 + 16]);
    bf16x8 kc2 = *reinterpret_cast<const bf16x8*>(&k[kb0 + 32]);
    bf16x8 kc3 = *reinterpret_cast<const bf16x8*>(&k[kb0 + 48]);
    // ---- V loads from tiled layout: lane stride 64B, coalesced ----
    const size_t vb0 = ((size_t)kb * 320 + kvh * 64 + ql) * 32 + hi * 8;
    const size_t vb1 = ((size_t)kb * 320 + kvh * 64 + 32 + ql) * 32 + hi * 8;
    bf16x8 vc0 = *reinterpret_cast<const bf16x8*>(&vTb[vb0]);
    bf16x8 vc1 = *reinterpret_cast<const bf16x8*>(&vTb[vb0 + 16]);
    bf16x8 vc2 = *reinterpret_cast<const bf16x8*>(&vTb[vb1]);
    bf16x8 vc3 = *reinterpret_cast<const bf16x8*>(&vTb[vb1 + 16]);

    // ---- S^T = K · Q^T : two independent chains ----
    __builtin_amdgcn_s_setprio(1);
    f32x16 sa = {}, sb = {};
    sa = __builtin_amdgcn_mfma_f32_32x32x16_bf16(kc0, qf[0], sa, 0, 0, 0);
    sb = __builtin_amdgcn_mfma_f32_32x32x16_bf16(kc1, qf[1], sb, 0, 0, 0);
    sa = __builtin_amdgcn_mfma_f32_32x32x16_bf16(kc2, qf[2], sa, 0, 0, 0);
    sb = __builtin_amdgcn_mfma_f32_32x32x16_bf16(kc3, qf[3], sb, 0, 0, 0);
    __builtin_amdgcn_s_setprio(0);

    // ---- merge chains, scale, causal mask ----
    if (kvb + 31 > qrow) {
#pragma unroll
      for (int r = 0; r < 16; ++r) {
        const int kv = kvb + kvoff + (r & 3) + 8 * (r >> 2);
        float sv = (sa[r] + sb[r]) * 0.125f;
        sa[r] = (kv > qrow) ? -1e30f : sv;
      }
    } else {
#pragma unroll
      for (int r = 0; r < 16; ++r) sa[r] = (sa[r] + sb[r]) * 0.125f;
    }

    // ---- lane-local softmax (one cross-lane hop) ----
    float tm = sa[0];
#pragma unroll
    for (int r = 1; r < 16; ++r) tm = fmaxf(tm, sa[r]);
    tm = fmaxf(tm, __shfl_xor(tm, 32));
    const float mn = fmaxf(mrun, tm);
    const float ef = __expf(mrun - mn);
    mrun = mn;
    float ts = 0.f;
#pragma unroll
    for (int r = 0; r < 16; ++r) {
      float p = __expf(sa[r] - mn);
      sa[r] = p;
      ts += p;
    }
    ts += __shfl_xor(ts, 32);
    lrun = lrun * ef + ts;
#pragma unroll
    for (int r = 0; r < 16; ++r) { acc0[r] *= ef; acc1[r] *= ef; }

    // ---- P^T -> bf16 B-fragments (cvt_pk + xor32 exchange) ----
    unsigned int a0 = cvtpk(sa[0], sa[1]), a1 = cvtpk(sa[2], sa[3]);
    unsigned int a2 = cvtpk(sa[4], sa[5]), a3 = cvtpk(sa[6], sa[7]);
    unsigned int b0 = cvtpk(sa[8], sa[9]), b1 = cvtpk(sa[10], sa[11]);
    unsigned int b2 = cvtpk(sa[12], sa[13]), b3 = cvtpk(sa[14], sa[15]);
    unsigned int x0 = __shfl_xor(a0, 32), x1 = __shfl_xor(a1, 32);
    unsigned int x2 = __shfl_xor(a2, 32), x3 = __shfl_xor(a3, 32);
    unsigned int y0 = __shfl_xor(b0, 32), y1 = __shfl_xor(b1, 32);
    unsigned int y2 = __shfl_xor(b2, 32), y3 = __shfl_xor(b3, 32);
    union { unsigned int u[4]; bf16x8 v; } f0, f1;
    f0.u[0] = hi ? x2 : a0; f0.u[1] = hi ? x3 : a1;
    f0.u[2] = hi ? a2 : x0; f0.u[3] = hi ? a3 : x1;
    f1.u[0] = hi ? y2 : b0; f1.u[1] = hi ? y3 : b1;
    f1.u[2] = hi ? b2 : y0; f1.u[3] = hi ? b3 : y1;

    // ---- O^T += V^T · P^T : two independent chains ----
    __builtin_amdgcn_s_setprio(1);
    acc0 = __builtin_amdgcn_mfma_f32_32x32x16_bf16(vc0, f0.v, acc0, 0, 0, 0);
    acc1 = __builtin_amdgcn_mfma_f32_32x32x16_bf16(vc2, f0.v, acc1, 0, 0, 0);
    acc0 = __builtin_amdgcn_mfma_f32_32x32x16_bf16(vc1, f1.v, acc0, 0, 0, 0);
    acc1 = __builtin_amdgcn_mfma_f32_32x32x16_bf16(vc3, f1.v, acc1, 0, 0, 0);
    __builtin_amdgcn_s_setprio(0);
  }

  // ---- write partials (bf16): pacc[job][d=64][q=32] ----
  const size_t base = (((size_t)head * 64 + qt) * 8 + c) * 2048;
#pragma unroll
  for (int r = 0; r < 16; ++r) {
    const int row = (r & 3) + 8 * (r >> 2) + kvoff;
    pacc[base + (size_t)row * 32 + ql] = __float2bfloat16(acc0[r]);
    pacc[base + (size_t)(row + 32) * 32 + ql] = __float2bfloat16(acc1[r]);
  }
  const size_t mb = (((size_t)head * 64 + qt) * 8 + c) * 64;
  if (!hi) {
    pml[mb + ql * 2] = mrun;
    pml[mb + ql * 2 + 1] = lrun;
  }
}

// ---------------- attention merge: combine <=8 chunks -----------------------
__launch_bounds__(256)
__global__ void attn_merge3(const bf16* __restrict__ pacc, const float* __restrict__ pml,
                            bf16* __restrict__ ctx) {
  const int qt = blockIdx.x, head = blockIdx.y;
  const int nch = qt / 8 + 1;
  const size_t base = (((size_t)head * 64 + qt) * 8) * 2048;
  const size_t mb = (((size_t)head * 64 + qt) * 8) * 64;
  for (int i = threadIdx.x; i < 2048; i += 256) {
    const int qi = i >> 6, d = i & 63;
    float m = -1e30f;
    for (int c = 0; c < nch; ++c) m = fmaxf(m, pml[mb + c * 64 + qi * 2]);
    float lsum = 0.f, o = 0.f;
    for (int c = 0; c < nch; ++c) {
      float e = __expf(pml[mb + c * 64 + qi * 2] - m);
      lsum += pml[mb + c * 64 + qi * 2 + 1] * e;
      o += __bfloat162float(pacc[base + c * 2048 + d * 32 + qi]) * e;
    }
    ctx[(size_t)(qt * 32 + qi) * 960 + head * 64 + d] = __float2bfloat16(o / lsum);
  }
}

// ---------------- launch ----------------------------------------------------
extern "C" void kernel_launch(void* const* d_in, const int* in_sizes, int n_in,
                              void* d_out, int out_size, void* d_ws, size_t ws_size,
                              hipStream_t stream) {
  const float* x  = (const float*)d_in[0];
  const float* wq = (const float*)d_in[1];
  const float* wk = (const float*)d_in[2];
  const float* wv = (const float*)d_in[3];
  const float* wo = (const float*)d_in[4];
  const float* wg = (const float*)d_in[5];
  const float* wu = (const float*)d_in[6];
  const float* wd = (const float*)d_in[7];
  const float* g1 = (const float*)d_in[8];
  const float* g2 = (const float*)d_in[9];
  float* out = (float*)d_out;

  char* ws = (char*)d_ws;
  bf16*   wT   = (bf16*)ws;                        // 19,660,800 B
  bf16*   pacc = (bf16*)(ws + 19660800);           // 31,457,280 B (bf16 partials)
  float*  pml  = (float*)(ws + 51118080);          // 1,966,080 B
  bf16*   hbuf = (bf16*)(ws + 53084160);           // 3,932,160
  bf16*   qr   = (bf16*)(ws + 57016320);           // 3,932,160
  bf16*   kr   = (bf16*)(ws + 60948480);           // 1,310,720
  bf16*   vTb  = (bf16*)(ws + 62259200);           // 1,310,720 (tiled V)
  bf16*   ctx  = (bf16*)(ws + 63569920);           // 3,932,160
  float*  x2   = (float*)(ws + 67502080);          // 7,864,320 (ends 75,366,400)
  float2* cst  = (float2*)(ws + 74842112);         // 524,288, overlaps x2 tail
                                                   // (cst dead before x2 written)
  bf16*   actb = (bf16*)(ws + 19660800);           // reuse pacc region after merge

  bf16* wqkvT = wT;           // 1600 rows x K=960: wq | wk | wv
  bf16* wkT  = wT + 921600;
  bf16* woT  = wT + 1536000;  // 960x960
  bf16* wguT = wT + 2457600;  // 5120x960 interleaved [gate16|up16]
  bf16* wdT  = wT + 7372800;  // 960x2560

  dim3 blk(256);
  prep_k<<<2656, blk, 0, stream>>>(wq, wk, wv, wo, wg, wu, wd,
                                   wqkvT, woT, wguT, wdT, cst);

  rmsnorm_k<<<2048, blk, 0, stream>>>(x, g1, hbuf);
  gemm_qkv<<<dim3(13, 32), blk, 0, stream>>>(hbuf, wqkvT, cst, qr, kr, vTb);
  attn_part5<<<dim3(64, 15, 8), dim3(64), 0, stream>>>(qr, kr, vTb, pacc, pml);
  attn_merge3<<<dim3(64, 15), blk, 0, stream>>>(pacc, pml, ctx);
  gemm_bt64<2><<<dim3(8, 32), dim3(512), 0, stream>>>(ctx, woT, x, x2, 960, 960);
  rmsnorm_k<<<2048, blk, 0, stream>>>(x2, g2, hbuf);
  gemm_ffn<<<dim3(40, 16), blk, 0, stream>>>(hbuf, wguT, actb);
  gemm_bt64<2><<<dim3(8, 32), dim3(512), 0, stream>>>(actb, wdT, x2, out, 960, 2560);
  rmsnorm_k<<<2048, blk, 0, stream>>>(x2, g1, hbuf);
  gemm_bt64<3><<<dim3(5, 32), dim3(512), 0, stream>>>(hbuf, wkT, nullptr, out + 1966080, 640, 960);
}

// Round 7
// 226.799 us; speedup vs baseline: 1.1349x; 1.0341x over previous
//
#include <hip/hip_runtime.h>
#include <hip/hip_bf16.h>

// TextEncoderBlock R6: coalesced attention merge (the hidden 43us), uniform
// diagonal-tile branch + defer-max rescale in attn_part. V kv-block-tiled,
// swapped-QK^T lane-local softmax, SwiGLU fused FFN, RoPE fused QKV.
// B=1 L=2048 EMBD=960 FFN=2560 QH=15 KVH=5 HD=64

typedef __hip_bfloat16 bf16;
typedef __attribute__((ext_vector_type(8))) short bf16x8;
typedef __attribute__((ext_vector_type(4))) float f32x4;
typedef __attribute__((ext_vector_type(16))) float f32x16;

#define EPS 1.1920929e-07f

__device__ __forceinline__ void gload_lds16(const bf16* g, bf16* l) {
  __builtin_amdgcn_global_load_lds(
      (const __attribute__((address_space(1))) unsigned int*)g,
      (__attribute__((address_space(3))) unsigned int*)l, 16, 0, 0);
}

__device__ __forceinline__ unsigned short f2bfu(float f) {
  __hip_bfloat16 b = __float2bfloat16(f);
  return *reinterpret_cast<unsigned short*>(&b);
}
__device__ __forceinline__ float bfu2f(unsigned short u) {
  return __uint_as_float(((unsigned int)u) << 16);
}
__device__ __forceinline__ unsigned int cvtpk(float lo, float hi_) {
  unsigned int r;
  asm("v_cvt_pk_bf16_f32 %0, %1, %2" : "=v"(r) : "v"(lo), "v"(hi_));
  return r;
}

// ---------------- fused prep: 7 weight transposes + rope table --------------
__device__ void do_transpose(float (*tile)[65], const float* __restrict__ W,
                             bf16* __restrict__ WT, int K, int N, int bx, int by,
                             int map) {
  const int k0 = by * 64, n0 = bx * 64;
  const int tx = threadIdx.x & 63, ty = threadIdx.x >> 6;
#pragma unroll
  for (int i = 0; i < 16; ++i) {
    int r = ty + i * 4;
    tile[r][tx] = W[(size_t)(k0 + r) * N + n0 + tx];
  }
  __syncthreads();
#pragma unroll
  for (int i = 0; i < 16; ++i) {
    int r = ty + i * 4;
    int v = n0 + r;
    int row = (map == 0) ? v : ((v >> 4) << 5) + (v & 15) + (map == 2 ? 16 : 0);
    WT[(size_t)row * K + k0 + tx] = __float2bfloat16(tile[tx][r]);
  }
}

__launch_bounds__(256)
__global__ void prep_k(const float* __restrict__ wq, const float* __restrict__ wk,
                       const float* __restrict__ wv, const float* __restrict__ wo,
                       const float* __restrict__ wg, const float* __restrict__ wu,
                       const float* __restrict__ wd, bf16* __restrict__ wqkvT,
                       bf16* __restrict__ woT, bf16* __restrict__ wguT,
                       bf16* __restrict__ wdT, float2* __restrict__ cstab) {
  __shared__ float tile[64][65];
  int b = blockIdx.x;
  if (b < 225) {
    do_transpose(tile, wq, wqkvT, 960, 960, b % 15, b / 15, 0);
  } else if (b < 300) {
    b -= 225;
    do_transpose(tile, wk, wqkvT + 921600, 960, 320, b % 5, b / 5, 0);
  } else if (b < 375) {
    b -= 300;
    do_transpose(tile, wv, wqkvT + 1228800, 960, 320, b % 5, b / 5, 0);
  } else if (b < 600) {
    b -= 375;
    do_transpose(tile, wo, woT, 960, 960, b % 15, b / 15, 0);
  } else if (b < 1200) {
    b -= 600;
    do_transpose(tile, wg, wguT, 960, 2560, b % 40, b / 40, 1);
  } else if (b < 1800) {
    b -= 1200;
    do_transpose(tile, wu, wguT, 960, 2560, b % 40, b / 40, 2);
  } else if (b < 2400) {
    b -= 1800;
    do_transpose(tile, wd, wdT, 2560, 960, b % 15, b / 15, 0);
  } else {
    const int idx = (b - 2400) * 256 + threadIdx.x;
    const int pos = idx >> 5, d = idx & 31;
    float inv = powf(10000.f, -(float)d * (1.f / 32.f));
    float rad = (float)pos * inv;
    cstab[idx] = make_float2(cosf(rad), sinf(rad));
  }
}

// ---------------- rmsnorm ---------------------------------------------------
__launch_bounds__(256)
__global__ void rmsnorm_k(const float* __restrict__ x, const float* __restrict__ g,
                          bf16* __restrict__ out) {
  const int row = blockIdx.x;
  const float* xr = x + (size_t)row * 960;
  const int t = threadIdx.x;
  float4 v = {0.f, 0.f, 0.f, 0.f};
  float ss = 0.f;
  if (t < 240) {
    v = *reinterpret_cast<const float4*>(&xr[t * 4]);
    ss = v.x * v.x + v.y * v.y + v.z * v.z + v.w * v.w;
  }
#pragma unroll
  for (int off = 32; off; off >>= 1) ss += __shfl_down(ss, off);
  __shared__ float red[4];
  __shared__ float s_scale;
  if ((t & 63) == 0) red[t >> 6] = ss;
  __syncthreads();
  if (t == 0) {
    float tot = red[0] + red[1] + red[2] + red[3];
    s_scale = rsqrtf(tot * (1.f / 960.f) + EPS);
  }
  __syncthreads();
  if (t < 240) {
    const float sc = s_scale;
    const float4 gv = *reinterpret_cast<const float4*>(&g[t * 4]);
    ushort4 o;
    o.x = f2bfu(v.x * sc * gv.x);
    o.y = f2bfu(v.y * sc * gv.y);
    o.z = f2bfu(v.z * sc * gv.z);
    o.w = f2bfu(v.w * sc * gv.w);
    *reinterpret_cast<ushort4*>(&out[(size_t)row * 960 + t * 4]) = o;
  }
}

// ---------------- FFN GEMM 128x128, fused SwiGLU epilogue -------------------
__launch_bounds__(256)
__global__ void gemm_ffn(const bf16* __restrict__ A, const bf16* __restrict__ BT,
                         bf16* __restrict__ actb) {
  const int K = 960;
  __shared__ __align__(16) bf16 sA[2][128 * 32];
  __shared__ __align__(16) bf16 sB[2][128 * 32];
  const int t = threadIdx.x, w = t >> 6, lane = t & 63;
  const int lg = lane >> 4, lr = lane & 15;
  const int wm = w >> 1, wn = w & 1;
  const int m0 = blockIdx.y * 128, n0 = blockIdx.x * 128;
  f32x4 acc[4][4] = {};
  const int nsteps = K / 32;

  auto stage = [&](int buf, int ks) {
    const int k0 = ks * 32;
#pragma unroll
    for (int i = 0; i < 2; ++i) {
      int c = w * 128 + i * 64 + lane;
      int r = c >> 2, kc = (c & 3) * 8;
      gload_lds16(A + (size_t)(m0 + r) * K + k0 + kc, &sA[buf][c * 8]);
      gload_lds16(BT + (size_t)(n0 + r) * K + k0 + kc, &sB[buf][c * 8]);
    }
  };

  stage(0, 0);
  __syncthreads();
  int cur = 0;
  for (int ks = 0; ks < nsteps; ++ks) {
    if (ks + 1 < nsteps) stage(cur ^ 1, ks + 1);
    bf16x8 af[4], bfr[4];
#pragma unroll
    for (int mi = 0; mi < 4; ++mi)
      af[mi] = *reinterpret_cast<const bf16x8*>(&sA[cur][(wm * 64 + mi * 16 + lr) * 32 + lg * 8]);
#pragma unroll
    for (int ni = 0; ni < 4; ++ni)
      bfr[ni] = *reinterpret_cast<const bf16x8*>(&sB[cur][(wn * 64 + ni * 16 + lr) * 32 + lg * 8]);
#pragma unroll
    for (int mi = 0; mi < 4; ++mi)
#pragma unroll
      for (int ni = 0; ni < 4; ++ni)
        acc[mi][ni] = __builtin_amdgcn_mfma_f32_16x16x32_bf16(af[mi], bfr[ni], acc[mi][ni], 0, 0, 0);
    __syncthreads();
    cur ^= 1;
  }

  const int colbase = n0 + wn * 64;
#pragma unroll
  for (int mi = 0; mi < 4; ++mi) {
    const int row = m0 + wm * 64 + mi * 16 + lg * 4;
#pragma unroll
    for (int p = 0; p < 2; ++p) {
      const int oc = ((colbase >> 5) + p) * 16 + lr;
#pragma unroll
      for (int r = 0; r < 4; ++r) {
        float gf = acc[mi][2 * p][r], uf = acc[mi][2 * p + 1][r];
        float s = gf / (1.f + __expf(-gf));
        actb[(size_t)(row + r) * 2560 + oc] = __float2bfloat16(s * uf);
      }
    }
  }
}

// ---------------- GEMM 64x128, 8 waves (512 thr): MODE 2 +=Res, MODE 3 kv ---
template <int MODE>
__launch_bounds__(512)
__global__ void gemm_bt64(const bf16* __restrict__ A, const bf16* __restrict__ BT,
                          const float* __restrict__ Res, float* __restrict__ Cf,
                          int N, int K) {
  __shared__ __align__(16) bf16 sA[2][64 * 32];
  __shared__ __align__(16) bf16 sB[2][128 * 32];
  const int t = threadIdx.x, w = t >> 6, lane = t & 63;
  const int lg = lane >> 4, lr = lane & 15;
  const int wm = w >> 2, wn = w & 3;  // 2 x 4 waves, each 32x32
  const int m0 = blockIdx.y * 64, n0 = blockIdx.x * 128;
  f32x4 acc[2][2] = {};
  const int nsteps = K / 32;

  auto stage = [&](int buf, int ks) {
    const int k0 = ks * 32;
    if (t < 256) {
      int c = t;
      int r = c >> 2, kc = (c & 3) * 8;
      gload_lds16(A + (size_t)(m0 + r) * K + k0 + kc, &sA[buf][c * 8]);
    }
    {
      int c = t;
      int r = c >> 2, kc = (c & 3) * 8;
      int br = n0 + r;
      if (br >= N) br = N - 1;
      gload_lds16(BT + (size_t)br * K + k0 + kc, &sB[buf][c * 8]);
    }
  };

  stage(0, 0);
  __syncthreads();
  int cur = 0;
  for (int ks = 0; ks < nsteps; ++ks) {
    if (ks + 1 < nsteps) stage(cur ^ 1, ks + 1);
    bf16x8 af[2], bfr[2];
#pragma unroll
    for (int mi = 0; mi < 2; ++mi)
      af[mi] = *reinterpret_cast<const bf16x8*>(&sA[cur][(wm * 32 + mi * 16 + lr) * 32 + lg * 8]);
#pragma unroll
    for (int ni = 0; ni < 2; ++ni)
      bfr[ni] = *reinterpret_cast<const bf16x8*>(&sB[cur][(wn * 32 + ni * 16 + lr) * 32 + lg * 8]);
#pragma unroll
    for (int mi = 0; mi < 2; ++mi)
#pragma unroll
      for (int ni = 0; ni < 2; ++ni)
        acc[mi][ni] = __builtin_amdgcn_mfma_f32_16x16x32_bf16(af[mi], bfr[ni], acc[mi][ni], 0, 0, 0);
    __syncthreads();
    cur ^= 1;
  }

#pragma unroll
  for (int mi = 0; mi < 2; ++mi) {
    const int row = m0 + wm * 32 + mi * 16 + lg * 4;
#pragma unroll
    for (int ni = 0; ni < 2; ++ni) {
      const int col = n0 + wn * 32 + ni * 16 + lr;
      if (col < N) {
#pragma unroll
        for (int r = 0; r < 4; ++r) {
          float v = acc[mi][ni][r];
          size_t idx = (size_t)(row + r) * N + col;
          if (MODE == 2) {
            Cf[idx] = v + Res[idx];
          } else {
            int rr = row + r;
            if (col < 320)
              Cf[(size_t)rr * 320 + col] = v;
            else
              Cf[655360 + (size_t)rr * 320 + (col - 320)] = v;
          }
        }
      }
    }
  }
}

// ---------------- QKV GEMM 64x128 with fused RoPE + V-tiled epilogue --------
// vTb layout: [posblk 0..63][d 0..319][pos_in_blk 0..31]
__launch_bounds__(256)
__global__ void gemm_qkv(const bf16* __restrict__ A, const bf16* __restrict__ BT,
                         const float2* __restrict__ cstab, bf16* __restrict__ qr,
                         bf16* __restrict__ kr, bf16* __restrict__ vTb) {
  const int N = 1600, K = 960;
  __shared__ __align__(16) bf16 sA[2][64 * 32];
  __shared__ __align__(16) bf16 sB[2][128 * 32];
  const int t = threadIdx.x, w = t >> 6, lane = t & 63;
  const int lg = lane >> 4, lr = lane & 15;
  const int wm = w >> 1, wn = w & 1;
  const int m0 = blockIdx.y * 64, n0 = blockIdx.x * 128;
  f32x4 acc[2][4] = {};
  const int nsteps = K / 32;

  auto stage = [&](int buf, int ks) {
    const int k0 = ks * 32;
    {
      int c = t;
      int r = c >> 2, kc = (c & 3) * 8;
      gload_lds16(A + (size_t)(m0 + r) * K + k0 + kc, &sA[buf][c * 8]);
    }
#pragma unroll
    for (int i = 0; i < 2; ++i) {
      int c = i * 256 + t;
      int r = c >> 2, kc = (c & 3) * 8;
      int br = n0 + r;
      if (br >= N) br = N - 1;
      gload_lds16(BT + (size_t)br * K + k0 + kc, &sB[buf][c * 8]);
    }
  };

  stage(0, 0);
  __syncthreads();
  int cur = 0;
  for (int ks = 0; ks < nsteps; ++ks) {
    if (ks + 1 < nsteps) stage(cur ^ 1, ks + 1);
    bf16x8 af[2], bfr[4];
#pragma unroll
    for (int mi = 0; mi < 2; ++mi)
      af[mi] = *reinterpret_cast<const bf16x8*>(&sA[cur][(wm * 32 + mi * 16 + lr) * 32 + lg * 8]);
#pragma unroll
    for (int ni = 0; ni < 4; ++ni)
      bfr[ni] = *reinterpret_cast<const bf16x8*>(&sB[cur][(wn * 64 + ni * 16 + lr) * 32 + lg * 8]);
#pragma unroll
    for (int mi = 0; mi < 2; ++mi)
#pragma unroll
      for (int ni = 0; ni < 4; ++ni)
        acc[mi][ni] = __builtin_amdgcn_mfma_f32_16x16x32_bf16(af[mi], bfr[ni], acc[mi][ni], 0, 0, 0);
    __syncthreads();
    cur ^= 1;
  }

  const int colbase = n0 + wn * 64;
  if (colbase >= 1600) return;
  if (colbase < 1280) {
    const bool isq = colbase < 960;
    bf16* dst = isq ? qr : kr;
    const int ncols = isq ? 960 : 320;
    const int cb = isq ? colbase : colbase - 960;
#pragma unroll
    for (int mi = 0; mi < 2; ++mi) {
      const int row = m0 + wm * 32 + mi * 16 + lg * 4;
#pragma unroll
      for (int ni = 0; ni < 2; ++ni) {
        const int d = ni * 16 + lr;
#pragma unroll
        for (int r = 0; r < 4; ++r) {
          const int pos = row + r;
          float2 cs = cstab[pos * 32 + d];
          float x1 = acc[mi][ni][r], x2 = acc[mi][ni + 2][r];
          dst[(size_t)pos * ncols + cb + d] = __float2bfloat16(x1 * cs.x - x2 * cs.y);
          dst[(size_t)pos * ncols + cb + d + 32] = __float2bfloat16(x2 * cs.x + x1 * cs.y);
        }
      }
    }
  } else {
#pragma unroll
    for (int mi = 0; mi < 2; ++mi) {
      const int row = m0 + wm * 32 + mi * 16 + lg * 4;  // pos base (mult of 4)
#pragma unroll
      for (int ni = 0; ni < 4; ++ni) {
        const int vc = colbase - 1280 + ni * 16 + lr;
        ushort4 pk;
        pk.x = f2bfu(acc[mi][ni][0]);
        pk.y = f2bfu(acc[mi][ni][1]);
        pk.z = f2bfu(acc[mi][ni][2]);
        pk.w = f2bfu(acc[mi][ni][3]);
        *reinterpret_cast<ushort4*>(
            &vTb[((size_t)(row >> 5) * 320 + vc) * 32 + (row & 31)]) = pk;
      }
    }
  }
}

// ---------------- swapped-QK^T flash attention, KVBLK=32, tiled V -----------
// grid (64 qt, 15 head, 8 chunk of 256 kv), block 64 (1 wave).
__launch_bounds__(64)
__global__ void attn_part6(const bf16* __restrict__ q, const bf16* __restrict__ k,
                           const bf16* __restrict__ vTb, bf16* __restrict__ pacc,
                           float* __restrict__ pml) {
  const int qt = blockIdx.x, head = blockIdx.y, c = blockIdx.z;
  const int t0 = c * 8;
  if (t0 > qt) return;
  const int t1 = min(t0 + 8, qt + 1);
  const int lane = threadIdx.x & 63;
  const int ql = lane & 31;
  const int hi = lane >> 5;
  const int q0 = qt * 32;
  const int kvh = head / 3;
  const int qrow = q0 + ql;
  const int kvoff = 4 * hi;

  bf16x8 qf[4];
#pragma unroll
  for (int i = 0; i < 4; ++i)
    qf[i] = *reinterpret_cast<const bf16x8*>(
        &q[(size_t)(q0 + ql) * 960 + head * 64 + i * 16 + hi * 8]);

  f32x16 acc0 = {}, acc1 = {};
  float mrun = -1e30f, lrun = 0.f;
  const bf16* kp = k + (size_t)ql * 320 + kvh * 64 + hi * 8 + (size_t)t0 * 32 * 320;
  const bf16* vp = vTb + ((size_t)t0 * 320 + kvh * 64 + ql) * 32 + hi * 8;

  for (int kb = t0; kb < t1; ++kb) {
    // ---- K loads (row stride 640B) ----
    bf16x8 kc0 = *reinterpret_cast<const bf16x8*>(kp);
    bf16x8 kc1 = *reinterpret_cast<const bf16x8*>(kp + 16);
    bf16x8 kc2 = *reinterpret_cast<const bf16x8*>(kp + 32);
    bf16x8 kc3 = *reinterpret_cast<const bf16x8*>(kp + 48);
    // ---- V loads (tiled: lane stride 64B) ----
    bf16x8 vc0 = *reinterpret_cast<const bf16x8*>(vp);
    bf16x8 vc1 = *reinterpret_cast<const bf16x8*>(vp + 16);
    bf16x8 vc2 = *reinterpret_cast<const bf16x8*>(vp + 32 * 32);
    bf16x8 vc3 = *reinterpret_cast<const bf16x8*>(vp + 32 * 32 + 16);

    // ---- S^T = K · Q^T : two independent chains ----
    __builtin_amdgcn_s_setprio(1);
    f32x16 sa = {}, sb = {};
    sa = __builtin_amdgcn_mfma_f32_32x32x16_bf16(kc0, qf[0], sa, 0, 0, 0);
    sb = __builtin_amdgcn_mfma_f32_32x32x16_bf16(kc1, qf[1], sb, 0, 0, 0);
    sa = __builtin_amdgcn_mfma_f32_32x32x16_bf16(kc2, qf[2], sa, 0, 0, 0);
    sb = __builtin_amdgcn_mfma_f32_32x32x16_bf16(kc3, qf[3], sb, 0, 0, 0);
    __builtin_amdgcn_s_setprio(0);

    // ---- merge chains, scale, causal mask (wave-uniform diagonal branch) ----
    if (kb == qt) {
      const int kvb = kb * 32;
#pragma unroll
      for (int r = 0; r < 16; ++r) {
        const int kv = kvb + kvoff + (r & 3) + 8 * (r >> 2);
        float sv = (sa[r] + sb[r]) * 0.125f;
        sa[r] = (kv > qrow) ? -1e30f : sv;
      }
    } else {
#pragma unroll
      for (int r = 0; r < 16; ++r) sa[r] = (sa[r] + sb[r]) * 0.125f;
    }

    // ---- lane-local softmax with defer-max (T13, THR=8) ----
    float tm = sa[0];
#pragma unroll
    for (int r = 1; r < 16; ++r) tm = fmaxf(tm, sa[r]);
    tm = fmaxf(tm, __shfl_xor(tm, 32));
    if (__any(tm > mrun + 8.f)) {
      const float mn = fmaxf(mrun, tm);
      const float ef = __expf(mrun - mn);
      mrun = mn;
#pragma unroll
      for (int r = 0; r < 16; ++r) { acc0[r] *= ef; acc1[r] *= ef; }
      lrun *= ef;
    }
    float ts = 0.f;
#pragma unroll
    for (int r = 0; r < 16; ++r) {
      float p = __expf(sa[r] - mrun);
      sa[r] = p;
      ts += p;
    }
    ts += __shfl_xor(ts, 32);
    lrun += ts;

    // ---- P^T -> bf16 B-fragments (cvt_pk + xor32 exchange) ----
    unsigned int a0 = cvtpk(sa[0], sa[1]), a1 = cvtpk(sa[2], sa[3]);
    unsigned int a2 = cvtpk(sa[4], sa[5]), a3 = cvtpk(sa[6], sa[7]);
    unsigned int b0 = cvtpk(sa[8], sa[9]), b1 = cvtpk(sa[10], sa[11]);
    unsigned int b2 = cvtpk(sa[12], sa[13]), b3 = cvtpk(sa[14], sa[15]);
    unsigned int x0 = __shfl_xor(a0, 32), x1 = __shfl_xor(a1, 32);
    unsigned int x2 = __shfl_xor(a2, 32), x3 = __shfl_xor(a3, 32);
    unsigned int y0 = __shfl_xor(b0, 32), y1 = __shfl_xor(b1, 32);
    unsigned int y2 = __shfl_xor(b2, 32), y3 = __shfl_xor(b3, 32);
    union { unsigned int u[4]; bf16x8 v; } f0, f1;
    f0.u[0] = hi ? x2 : a0; f0.u[1] = hi ? x3 : a1;
    f0.u[2] = hi ? a2 : x0; f0.u[3] = hi ? a3 : x1;
    f1.u[0] = hi ? y2 : b0; f1.u[1] = hi ? y3 : b1;
    f1.u[2] = hi ? b2 : y0; f1.u[3] = hi ? b3 : y1;

    // ---- O^T += V^T · P^T : two independent chains ----
    __builtin_amdgcn_s_setprio(1);
    acc0 = __builtin_amdgcn_mfma_f32_32x32x16_bf16(vc0, f0.v, acc0, 0, 0, 0);
    acc1 = __builtin_amdgcn_mfma_f32_32x32x16_bf16(vc2, f0.v, acc1, 0, 0, 0);
    acc0 = __builtin_amdgcn_mfma_f32_32x32x16_bf16(vc1, f1.v, acc0, 0, 0, 0);
    acc1 = __builtin_amdgcn_mfma_f32_32x32x16_bf16(vc3, f1.v, acc1, 0, 0, 0);
    __builtin_amdgcn_s_setprio(0);

    kp += 32 * 320;
    vp += 320 * 32;
  }

  // ---- write partials (bf16): pacc[job][d=64][q=32] ----
  const size_t base = (((size_t)head * 64 + qt) * 8 + c) * 2048;
#pragma unroll
  for (int r = 0; r < 16; ++r) {
    const int row = (r & 3) + 8 * (r >> 2) + kvoff;
    pacc[base + (size_t)row * 32 + ql] = __float2bfloat16(acc0[r]);
    pacc[base + (size_t)(row + 32) * 32 + ql] = __float2bfloat16(acc1[r]);
  }
  const size_t mb = (((size_t)head * 64 + qt) * 8 + c) * 64;
  if (!hi) {
    pml[mb + ql * 2] = mrun;
    pml[mb + ql * 2 + 1] = lrun;
  }
}

// ---------------- attention merge: coalesced reads + LDS transpose ----------
// grid (64 qt, 15 head), 256 threads.
__launch_bounds__(256)
__global__ void attn_merge4(const bf16* __restrict__ pacc, const float* __restrict__ pml,
                            bf16* __restrict__ ctx) {
  const int qt = blockIdx.x, head = blockIdx.y;
  const int nch = qt / 8 + 1;
  const size_t base = (((size_t)head * 64 + qt) * 8) * 2048;
  const size_t mb = (((size_t)head * 64 + qt) * 8) * 64;
  __shared__ float smem[32][65];
  for (int i = threadIdx.x; i < 2048; i += 256) {
    const int qi = i & 31, d = i >> 5;  // lane-consecutive -> contiguous pacc
    float m = -1e30f;
    for (int c = 0; c < nch; ++c) m = fmaxf(m, pml[mb + c * 64 + qi * 2]);
    float lsum = 0.f, o = 0.f;
    for (int c = 0; c < nch; ++c) {
      float e = __expf(pml[mb + c * 64 + qi * 2] - m);
      lsum += pml[mb + c * 64 + qi * 2 + 1] * e;
      o += __bfloat162float(pacc[base + c * 2048 + d * 32 + qi]) * e;
    }
    smem[qi][d] = o / lsum;
  }
  __syncthreads();
  for (int i = threadIdx.x; i < 2048; i += 256) {
    const int qi = i >> 6, d = i & 63;  // d fastest -> coalesced ctx store
    ctx[(size_t)(qt * 32 + qi) * 960 + head * 64 + d] = __float2bfloat16(smem[qi][d]);
  }
}

// ---------------- launch ----------------------------------------------------
extern "C" void kernel_launch(void* const* d_in, const int* in_sizes, int n_in,
                              void* d_out, int out_size, void* d_ws, size_t ws_size,
                              hipStream_t stream) {
  const float* x  = (const float*)d_in[0];
  const float* wq = (const float*)d_in[1];
  const float* wk = (const float*)d_in[2];
  const float* wv = (const float*)d_in[3];
  const float* wo = (const float*)d_in[4];
  const float* wg = (const float*)d_in[5];
  const float* wu = (const float*)d_in[6];
  const float* wd = (const float*)d_in[7];
  const float* g1 = (const float*)d_in[8];
  const float* g2 = (const float*)d_in[9];
  float* out = (float*)d_out;

  char* ws = (char*)d_ws;
  bf16*   wT   = (bf16*)ws;                        // 19,660,800 B
  bf16*   pacc = (bf16*)(ws + 19660800);           // 31,457,280 B (bf16 partials)
  float*  pml  = (float*)(ws + 51118080);          // 1,966,080 B
  bf16*   hbuf = (bf16*)(ws + 53084160);           // 3,932,160
  bf16*   qr   = (bf16*)(ws + 57016320);           // 3,932,160
  bf16*   kr   = (bf16*)(ws + 60948480);           // 1,310,720
  bf16*   vTb  = (bf16*)(ws + 62259200);           // 1,310,720 (tiled V)
  bf16*   ctx  = (bf16*)(ws + 63569920);           // 3,932,160
  float*  x2   = (float*)(ws + 67502080);          // 7,864,320 (ends 75,366,400)
  float2* cst  = (float2*)(ws + 74842112);         // 524,288, overlaps x2 tail
                                                   // (cst dead before x2 written)
  bf16*   actb = (bf16*)(ws + 19660800);           // reuse pacc region after merge

  bf16* wqkvT = wT;           // 1600 rows x K=960: wq | wk | wv
  bf16* wkT  = wT + 921600;
  bf16* woT  = wT + 1536000;  // 960x960
  bf16* wguT = wT + 2457600;  // 5120x960 interleaved [gate16|up16]
  bf16* wdT  = wT + 7372800;  // 960x2560

  dim3 blk(256);
  prep_k<<<2656, blk, 0, stream>>>(wq, wk, wv, wo, wg, wu, wd,
                                   wqkvT, woT, wguT, wdT, cst);

  rmsnorm_k<<<2048, blk, 0, stream>>>(x, g1, hbuf);
  gemm_qkv<<<dim3(13, 32), blk, 0, stream>>>(hbuf, wqkvT, cst, qr, kr, vTb);
  attn_part6<<<dim3(64, 15, 8), dim3(64), 0, stream>>>(qr, kr, vTb, pacc, pml);
  attn_merge4<<<dim3(64, 15), blk, 0, stream>>>(pacc, pml, ctx);
  gemm_bt64<2><<<dim3(8, 32), dim3(512), 0, stream>>>(ctx, woT, x, x2, 960, 960);
  rmsnorm_k<<<2048, blk, 0, stream>>>(x2, g2, hbuf);
  gemm_ffn<<<dim3(40, 16), blk, 0, stream>>>(hbuf, wguT, actb);
  gemm_bt64<2><<<dim3(8, 32), dim3(512), 0, stream>>>(actb, wdT, x2, out, 960, 2560);
  rmsnorm_k<<<2048, blk, 0, stream>>>(x2, g1, hbuf);
  gemm_bt64<3><<<dim3(5, 32), dim3(512), 0, stream>>>(hbuf, wkT, nullptr, out + 1966080, 640, 960);
}